// Round 1
// baseline (1277.742 us; speedup 1.0000x reference)
//
#include <hip/hip_runtime.h>

// k-means cluster step: N=400000 points, D=256, K=50 (fp32).
// out[0:12800]  = per-cluster sums (50x256, fp32)
// out[12800:12850] = per-cluster counts (written as fp32 values)

constexpr int K = 50;
constexpr int D = 256;
constexpr int SROW = D + 1;       // 257: padded LDS row stride (bank spread)
constexpr int OUT_N = K * D + K;  // 12850
constexpr int GRID = 768;         // 3 blocks/CU x 256 CU

__global__ __launch_bounds__(256, 3)
void kmeans_assign(const float* __restrict__ x, const float* __restrict__ c,
                   float* __restrict__ partial, float* __restrict__ out,
                   int N, int useAtomic) {
    __shared__ float s_sums[K * SROW];
    __shared__ float s_c2[K];
    __shared__ int   s_cnt[K];

    const int tid = threadIdx.x;
    for (int idx = tid; idx < K * SROW; idx += 256) s_sums[idx] = 0.f;
    if (tid < K) {
        s_cnt[tid] = 0;
        float s = 0.f;
        const float4* cr = (const float4*)(c + tid * D);
        for (int i = 0; i < D / 4; ++i) {
            float4 v = cr[i];
            s += v.x * v.x + v.y * v.y + v.z * v.z + v.w * v.w;
        }
        s_c2[tid] = s;
    }
    __syncthreads();

    const int lane = tid & 63;
    const int q    = lane & 3;    // quarter within point (owns chunks q,4+q,8+q,...)
    const int g    = lane >> 2;   // point index within group of 16
    const int waveId  = (blockIdx.x * 256 + tid) >> 6;
    const int nWaves  = gridDim.x * 4;
    const int nGroups = (N + 15) >> 4;

    for (int pg = waveId; pg < nGroups; pg += nWaves) {
        const int p = pg * 16 + g;
        const bool valid = (p < N);
        const float* xb = x + (size_t)p * D;

        // x row kept in registers: thread owns elements d with ((d>>2)&3)==q.
        // Per wave instruction (fixed i): 16 rows x contiguous 64B -> coalesced.
        float4 xr[16];
        #pragma unroll
        for (int i = 0; i < 16; ++i) {
            if (valid) xr[i] = *(const float4*)(xb + 16 * i + 4 * q);
            else       xr[i] = float4{0.f, 0.f, 0.f, 0.f};
        }

        float acc[K];
        #pragma unroll
        for (int k = 0; k < K; ++k) acc[k] = 0.f;

        #pragma unroll 1
        for (int i = 0; i < 16; ++i) {
            const float4 xv = xr[i];
            const float* cb = c + 16 * i + 4 * q;
            #pragma unroll
            for (int k = 0; k < K; ++k) {
                const float4 cv = *(const float4*)(cb + (size_t)k * D);
                acc[k] = fmaf(xv.x, cv.x, acc[k]);
                acc[k] = fmaf(xv.y, cv.y, acc[k]);
                acc[k] = fmaf(xv.z, cv.z, acc[k]);
                acc[k] = fmaf(xv.w, cv.w, acc[k]);
            }
        }

        // quad butterfly: all 4 lanes get bitwise-identical full dot products
        #pragma unroll
        for (int k = 0; k < K; ++k) {
            float v = acc[k];
            v += __shfl_xor(v, 1, 64);
            v += __shfl_xor(v, 2, 64);
            acc[k] = v;
        }

        // argmin of c2 - 2*dot (same ordering as reference d2); first-min tie-break
        int best = 0;
        float bs = s_c2[0] - 2.f * acc[0];
        #pragma unroll
        for (int k = 1; k < K; ++k) {
            float s = s_c2[k] - 2.f * acc[k];
            if (s < bs) { bs = s; best = k; }
        }

        if (valid) {
            if (q == 0) atomicAdd(&s_cnt[best], 1);
            // LDS bank = (best + 16i + 4q + j) % 32 -> quads on distinct banks
            float* row = &s_sums[best * SROW + 4 * q];
            #pragma unroll
            for (int i = 0; i < 16; ++i) {
                atomicAdd(&row[16 * i + 0], xr[i].x);
                atomicAdd(&row[16 * i + 1], xr[i].y);
                atomicAdd(&row[16 * i + 2], xr[i].z);
                atomicAdd(&row[16 * i + 3], xr[i].w);
            }
        }
    }
    __syncthreads();

    if (useAtomic) {
        for (int idx = tid; idx < K * D; idx += 256) {
            int k = idx >> 8, d = idx & 255;
            atomicAdd(&out[idx], s_sums[k * SROW + d]);
        }
        for (int k2 = tid; k2 < K; k2 += 256)
            atomicAdd(&out[K * D + k2], (float)s_cnt[k2]);
    } else {
        float* pb = partial + (size_t)blockIdx.x * OUT_N;
        for (int idx = tid; idx < K * D; idx += 256) {
            int k = idx >> 8, d = idx & 255;
            pb[idx] = s_sums[k * SROW + d];
        }
        for (int k2 = tid; k2 < K; k2 += 256)
            pb[K * D + k2] = (float)s_cnt[k2];
    }
}

__global__ void kmeans_reduce(const float* __restrict__ partial,
                              float* __restrict__ out, int G) {
    int j = blockIdx.x * blockDim.x + threadIdx.x;
    if (j >= OUT_N) return;
    float s = 0.f;
    for (int b = 0; b < G; ++b) s += partial[(size_t)b * OUT_N + j];
    out[j] = s;
}

extern "C" void kernel_launch(void* const* d_in, const int* in_sizes, int n_in,
                              void* d_out, int out_size, void* d_ws, size_t ws_size,
                              hipStream_t stream) {
    const float* x = (const float*)d_in[0];
    const float* c = (const float*)d_in[1];
    float* out = (float*)d_out;
    const int N = in_sizes[0] / D;

    const size_t need = (size_t)GRID * OUT_N * sizeof(float);
    const int useAtomic = (ws_size < need) ? 1 : 0;

    if (useAtomic) {
        hipMemsetAsync(d_out, 0, (size_t)out_size * sizeof(float), stream);
    }
    kmeans_assign<<<GRID, 256, 0, stream>>>(x, c, (float*)d_ws, out, N, useAtomic);
    if (!useAtomic) {
        kmeans_reduce<<<(OUT_N + 255) / 256, 256, 0, stream>>>(
            (const float*)d_ws, out, GRID);
    }
}